// Round 5
// baseline (243.685 us; speedup 1.0000x reference)
//
#include <hip/hip_runtime.h>
#include <hip/hip_bf16.h>

// Problem constants (from reference)
#define N_PARENT 16384
#define N_CHILD (8 * N_PARENT)   // 131072
#define CC 128                   // channels
#define KK 27                    // stencil taps

// GEMM tiling: 128x128 block tile, 4 waves (2x2), 64x64 per wave, BK=64.
// A (gathered child features) lives in REGISTERS (per-lane global gather
// matches the MFMA A-fragment exactly); only B (weights) is LDS-staged.
#define BM 128
#define BN 128
#define BK 64
#define NSTAGE (KK * 2)          // 54 stages (27 taps x 2 c-halves)

// ws layout (bf16 element offsets)
#define XB_OFF 0
#define XB_ELEMS (N_PARENT * CC)             // 2,097,152
#define WT_OFF XB_ELEMS
#define WT_ELEMS (KK * CC * CC)              // 442,368
#define ZR_OFF (WT_OFF + WT_ELEMS)
#define ZR_ELEMS 128

typedef __attribute__((ext_vector_type(8))) __bf16 bf16x8;
typedef __attribute__((ext_vector_type(4))) float f32x4;

__device__ __forceinline__ void gll16(const void* g, void* l) {
  __builtin_amdgcn_global_load_lds(
      (const __attribute__((address_space(1))) unsigned int*)g,
      (__attribute__((address_space(3))) unsigned int*)l,
      16, 0, 0);
}

// Cast x to bf16, build w^T[k][d][c] in bf16, zero row.
__global__ void prep_kernel(const float* __restrict__ x,
                            const float* __restrict__ w,
                            __hip_bfloat16* __restrict__ ws) {
  const int stride = gridDim.x * blockDim.x;
  const int tid = blockIdx.x * blockDim.x + threadIdx.x;
  for (int i = tid; i < XB_ELEMS; i += stride)
    ws[XB_OFF + i] = __float2bfloat16(x[i]);
  for (int j = tid; j < WT_ELEMS; j += stride) {
    const int k = j / (CC * CC);
    const int rem = j - k * CC * CC;
    const int d = rem >> 7;   // output channel
    const int c = rem & 127;  // input channel
    ws[WT_OFF + j] = __float2bfloat16(w[k * CC * CC + c * CC + d]);
  }
  if (tid < ZR_ELEMS) ws[ZR_OFF + tid] = __float2bfloat16(0.0f);
}

// Sync scheme (per R3): issue batch(s+1) [4 gll16 + 8 reg loads = 12 vmem],
// vmcnt(12) -> batch(s) landed (B in LDS, A in regs), barrier, compute(s),
// barrier (WAR). B LDS swizzle: phys_col = log_col ^ (row&7)*8, inverse
// applied on the global source (gll16 dest linear).
__global__ __launch_bounds__(256, 2) void upconv_kernel(
    const int* __restrict__ neigh,
    const __hip_bfloat16* __restrict__ ws,
    const float* __restrict__ bias,
    float* __restrict__ out) {
  __shared__ __align__(16) __hip_bfloat16 Bs[2][BN * BK];  // 32 KB
  __shared__ short ridx[BM * KK];                          // 6.75 KB

  const __hip_bfloat16* xb = ws + XB_OFF;
  const __hip_bfloat16* wT = ws + WT_OFF;
  const __hip_bfloat16* zr = ws + ZR_OFF;

  const int tid = threadIdx.x;
  const int wv = tid >> 6;   // wave 0..3
  const int l = tid & 63;    // lane
  const int wr = wv >> 1;    // wave row (64-row strip)
  const int wc = wv & 1;     // wave col (64-col strip)
  const int row0 = blockIdx.x * BM;

  // Preload neighbor indices (coalesced), pre-shifted to parent rows.
  for (int j = tid; j < BM * KK; j += 256) {
    const int nv = neigh[row0 * KK + j];
    ridx[j] = (short)((nv >= 0) ? (nv >> 3) : -1);
  }
  __syncthreads();

  const int lr = l & 15;          // frag row within 16
  const int lk8 = (l >> 4) * 8;   // frag k-chunk offset (elements)
  const int lrow = l >> 3;        // staging: row within 8-row group
  const int scol = ((l & 7) ^ lrow) * 8;  // pre-swizzled global src col
  const int sw = (lr & 7) * 8;            // frag-read swizzle term

  f32x4 acc[4][4] = {};
  bf16x8 aP[8], aN[8];  // A fragments, double-buffered in registers

  // --- B staging: 4 gll16(16B)/wave/stage ---------------------------------
  auto stageB = [&](int buf, int k, int h) {
#pragma unroll
    for (int i = 0; i < 4; ++i) {
      const int dg = wv * 32 + i * 8;
      gll16(wT + (size_t)k * (CC * CC) + (size_t)(dg + lrow) * CC + h + scol,
            &Bs[buf][dg * BK]);
    }
  };

  // --- per-tap neighbor rows for this lane's frag rows --------------------
  int rid[4];
  auto loadRid = [&](int k) {
#pragma unroll
    for (int m = 0; m < 4; ++m)
      rid[m] = (int)ridx[(wr * 64 + m * 16 + lr) * KK + k];
  };

  // --- A gather, global -> registers: 8 x dwordx4 per stage ---------------
  auto loadA = [&](bf16x8* A, int h) {
#pragma unroll
    for (int m = 0; m < 4; ++m) {
      const __hip_bfloat16* base =
          (rid[m] >= 0) ? (xb + (size_t)rid[m] * CC + h + lk8) : (zr + lk8);
      A[m * 2 + 0] = *reinterpret_cast<const bf16x8*>(base);
      A[m * 2 + 1] = *reinterpret_cast<const bf16x8*>(base + 32);
    }
  };

  // --- compute: 8 swizzled ds_read_b128 + 32 MFMA per stage ---------------
  auto compute = [&](int buf, const bf16x8* A) {
#pragma unroll
    for (int kc = 0; kc < 2; ++kc) {
      bf16x8 b[4];
      const int ce = (kc * 32 + lk8) ^ sw;
#pragma unroll
      for (int n = 0; n < 4; ++n)
        b[n] = *reinterpret_cast<const bf16x8*>(
            &Bs[buf][(wc * 64 + n * 16 + lr) * BK + ce]);
      __builtin_amdgcn_s_setprio(1);
#pragma unroll
      for (int m = 0; m < 4; ++m)
#pragma unroll
        for (int n = 0; n < 4; ++n)
          acc[m][n] = __builtin_amdgcn_mfma_f32_16x16x32_bf16(
              A[m * 2 + kc], b[n], acc[m][n], 0, 0, 0);
      __builtin_amdgcn_s_setprio(0);
    }
  };

  // --- prologue: issue batch 0 (tap 0, h=0) -> buf0 / aP ------------------
  loadRid(0);
  stageB(0, 0, 0);
  loadA(aP, 0);

  // --- main loop: 27 taps x {even: h=0/buf0/aP, odd: h=64/buf1/aN} --------
  for (int k = 0; k < KK; ++k) {
    // even stage 2k: prefetch batch 2k+1 (same tap, h=64) -> buf1/aN
    stageB(1, k, 64);
    loadA(aN, 64);
    asm volatile("s_waitcnt vmcnt(12)" ::: "memory");  // batch 2k landed
    __builtin_amdgcn_s_barrier();
    compute(0, aP);
    __builtin_amdgcn_s_barrier();

    // odd stage 2k+1: prefetch batch 2k+2 (tap k+1, h=0) -> buf0/aP
    if (k + 1 < KK) {
      loadRid(k + 1);
      stageB(0, k + 1, 0);
      loadA(aP, 0);
      asm volatile("s_waitcnt vmcnt(12)" ::: "memory");  // batch 2k+1 landed
    } else {
      asm volatile("s_waitcnt vmcnt(0)" ::: "memory");   // final drain
    }
    __builtin_amdgcn_s_barrier();
    compute(1, aN);
    __builtin_amdgcn_s_barrier();
  }

  // --- epilogue: C/D layout col=lane&15, row=(lane>>4)*4+q ---------------
  float bv[4];
#pragma unroll
  for (int n = 0; n < 4; ++n) bv[n] = bias[wc * 64 + n * 16 + lr];
  const int rbase = row0 + wr * 64 + (l >> 4) * 4;
#pragma unroll
  for (int m = 0; m < 4; ++m)
#pragma unroll
    for (int n = 0; n < 4; ++n)
#pragma unroll
      for (int q = 0; q < 4; ++q)
        out[(size_t)(rbase + m * 16 + q) * CC + wc * 64 + n * 16 + lr] =
            acc[m][n][q] + bv[n];
}

extern "C" void kernel_launch(void* const* d_in, const int* in_sizes, int n_in,
                              void* d_out, int out_size, void* d_ws,
                              size_t ws_size, hipStream_t stream) {
  const float* x = (const float*)d_in[0];
  const float* w = (const float*)d_in[1];
  const float* b = (const float*)d_in[2];
  const int* neigh = (const int*)d_in[3];
  __hip_bfloat16* ws = (__hip_bfloat16*)d_ws;
  float* out = (float*)d_out;

  hipLaunchKernelGGL(prep_kernel, dim3(512), dim3(256), 0, stream, x, w, ws);
  hipLaunchKernelGGL(upconv_kernel, dim3(N_CHILD / BM), dim3(256), 0, stream,
                     neigh, ws, b, out);
}

// Round 6
// 136.392 us; speedup vs baseline: 1.7867x; 1.7867x over previous
//
#include <hip/hip_runtime.h>
#include <hip/hip_bf16.h>

// Problem constants (from reference)
#define N_PARENT 16384
#define N_CHILD (8 * N_PARENT)   // 131072
#define CC 128                   // channels
#define KK 27                    // stencil taps

// GEMM tiling: 128x128 block tile, 4 waves (2x2), 64x64 per wave, BK=64
#define BM 128
#define BN 128
#define BK 64

// ws layout (bf16 element offsets)
#define XB_OFF 0
#define XB_ELEMS (N_PARENT * CC)             // 2,097,152
#define WT_OFF XB_ELEMS
#define WT_ELEMS (KK * CC * CC)              // 442,368
#define ZR_OFF (WT_OFF + WT_ELEMS)
#define ZR_ELEMS 128
#define ZR_BYTE (ZR_OFF * 2)                 // zero-row byte offset from xb

typedef __attribute__((ext_vector_type(8))) __bf16 bf16x8;
typedef __attribute__((ext_vector_type(4))) float f32x4;

__device__ __forceinline__ void gll16(const void* g, void* l) {
  __builtin_amdgcn_global_load_lds(
      (const __attribute__((address_space(1))) unsigned int*)g,
      (__attribute__((address_space(3))) unsigned int*)l,
      16, 0, 0);
}

// Cast x to bf16, build w^T[k][d][c] in bf16, zero row.
__global__ void prep_kernel(const float* __restrict__ x,
                            const float* __restrict__ w,
                            __hip_bfloat16* __restrict__ ws) {
  const int stride = gridDim.x * blockDim.x;
  const int tid = blockIdx.x * blockDim.x + threadIdx.x;
  for (int i = tid; i < XB_ELEMS; i += stride)
    ws[XB_OFF + i] = __float2bfloat16(x[i]);
  for (int j = tid; j < WT_ELEMS; j += stride) {
    const int k = j / (CC * CC);
    const int rem = j - k * CC * CC;
    const int d = rem >> 7;   // output channel
    const int c = rem & 127;  // input channel
    ws[WT_OFF + j] = __float2bfloat16(w[k * CC * CC + c * CC + d]);
  }
  if (tid < ZR_ELEMS) ws[ZR_OFF + tid] = __float2bfloat16(0.0f);
}

// R3 counted-vmcnt dbuf structure + address strength-reduction:
//  - ridx holds PREMULTIPLIED byte offsets (rid*256, or zero-row offset);
//    the missing-neighbor select is resolved at preload time (branchless
//    staging: addr = xb + off + const).
//  - B staging address is a running per-lane pointer (+=64 / +=CC*CC).
//  - compute() takes literal buffer index -> LDS offsets fold to imms.
// B/A LDS swizzle: phys_col = log_col ^ (row&7)*8, inverse applied on the
// global source column (gll16 dest linear).
__global__ __launch_bounds__(256, 2) void upconv_kernel(
    const int* __restrict__ neigh,
    const __hip_bfloat16* __restrict__ ws,
    const float* __restrict__ bias,
    float* __restrict__ out) {
  __shared__ __align__(16) __hip_bfloat16 As[2][BM * BK];  // 32 KB
  __shared__ __align__(16) __hip_bfloat16 Bs[2][BN * BK];  // 32 KB
  __shared__ int ridx[BM * KK];                            // 13.5 KB (byte offs)

  const int tid = threadIdx.x;
  const int wv = tid >> 6;   // wave 0..3
  const int l = tid & 63;    // lane
  const int wr = wv >> 1;    // wave row (64-row strip)
  const int wc = wv & 1;     // wave col (64-col strip)
  const int row0 = blockIdx.x * BM;

  // Preload neighbor indices (coalesced) as premultiplied byte offsets.
  for (int j = tid; j < BM * KK; j += 256) {
    const int nv = neigh[row0 * KK + j];
    ridx[j] = (nv >= 0) ? ((nv >> 3) << 8) : ZR_BYTE;
  }
  __syncthreads();

  const int lr = l & 15;          // frag row within 16
  const int lk8 = (l >> 4) * 8;   // frag k-chunk offset (elements)
  const int lrow = l >> 3;        // staging: row within 8-row group
  const int scol = ((l & 7) ^ lrow) * 8;  // pre-swizzled global src col
  const int sw = (lr & 7) * 8;            // frag-read swizzle term
  const int aLaneB = scol * 2;            // staging lane byte offset (A)

  const char* xbB = (const char*)(ws + XB_OFF);
  const __hip_bfloat16* wB = ws + WT_OFF + (wv * 32 + lrow) * CC + scol;

  f32x4 acc[4][4] = {};
  int roff[4];  // current tap's staging byte offsets (per lane)

  auto loadRid = [&](int k) {
#pragma unroll
    for (int i = 0; i < 4; ++i)
      roff[i] = ridx[(wv * 32 + i * 8 + lrow) * KK + k];
  };

  // --- staging: 8 gll16(16B)/wave/stage (4 A + 4 B) -----------------------
  auto stageA = [&](int buf, int hb) {  // hb: c-half byte offset (0 or 128)
#pragma unroll
    for (int i = 0; i < 4; ++i)
      gll16(xbB + roff[i] + hb + aLaneB, &As[buf][(wv * 32 + i * 8) * BK]);
  };
  auto stageB = [&](int buf, const __hip_bfloat16* wp) {
#pragma unroll
    for (int i = 0; i < 4; ++i)
      gll16(wp + i * 8 * CC, &Bs[buf][(wv * 32 + i * 8) * BK]);
  };

  // --- compute: 16 swizzled ds_read_b128 + 32 MFMA per stage --------------
  auto compute = [&](int buf) {
    const __hip_bfloat16* ap = As[buf];
    const __hip_bfloat16* bp = Bs[buf];
#pragma unroll
    for (int kc = 0; kc < 2; ++kc) {
      const int ce = (kc * 32 + lk8) ^ sw;
      bf16x8 a[4], b[4];
#pragma unroll
      for (int m = 0; m < 4; ++m)
        a[m] = *reinterpret_cast<const bf16x8*>(
            &ap[(wr * 64 + m * 16 + lr) * BK + ce]);
#pragma unroll
      for (int n = 0; n < 4; ++n)
        b[n] = *reinterpret_cast<const bf16x8*>(
            &bp[(wc * 64 + n * 16 + lr) * BK + ce]);
      __builtin_amdgcn_s_setprio(1);
#pragma unroll
      for (int m = 0; m < 4; ++m)
#pragma unroll
        for (int n = 0; n < 4; ++n)
          acc[m][n] = __builtin_amdgcn_mfma_f32_16x16x32_bf16(
              a[m], b[n], acc[m][n], 0, 0, 0);
      __builtin_amdgcn_s_setprio(0);
    }
  };

  // --- prologue: stage tap 0, h=0 -> buf0 ---------------------------------
  loadRid(0);
  stageB(0, wB);
  stageA(0, 0);

  // --- main loop: 27 taps x {even: h=0/buf0, odd: h=128B/buf1} ------------
  for (int k = 0; k < KK; ++k) {
    // even stage: prefetch same tap h=64 -> buf1; hoist next tap's rids
    stageB(1, wB + 64);
    stageA(1, 128);
    if (k + 1 < KK) loadRid(k + 1);  // lgkm, hides under vmcnt wait
    asm volatile("s_waitcnt vmcnt(8)" ::: "memory");  // batch 2k landed
    __builtin_amdgcn_s_barrier();
    compute(0);
    __builtin_amdgcn_s_barrier();

    // odd stage: prefetch tap k+1 h=0 -> buf0
    wB += CC * CC;
    if (k + 1 < KK) {
      stageB(0, wB);
      stageA(0, 0);
      asm volatile("s_waitcnt vmcnt(8)" ::: "memory");  // batch 2k+1 landed
    } else {
      asm volatile("s_waitcnt vmcnt(0)" ::: "memory");  // final drain
    }
    __builtin_amdgcn_s_barrier();
    compute(1);
    __builtin_amdgcn_s_barrier();
  }

  // --- epilogue: C/D layout col=lane&15, row=(lane>>4)*4+q ---------------
  float bv[4];
#pragma unroll
  for (int n = 0; n < 4; ++n) bv[n] = bias[wc * 64 + n * 16 + lr];
  const int rbase = row0 + wr * 64 + (l >> 4) * 4;
#pragma unroll
  for (int m = 0; m < 4; ++m)
#pragma unroll
    for (int n = 0; n < 4; ++n)
#pragma unroll
      for (int q = 0; q < 4; ++q)
        out[(size_t)(rbase + m * 16 + q) * CC + wc * 64 + n * 16 + lr] =
            acc[m][n][q] + bv[n];
}

extern "C" void kernel_launch(void* const* d_in, const int* in_sizes, int n_in,
                              void* d_out, int out_size, void* d_ws,
                              size_t ws_size, hipStream_t stream) {
  const float* x = (const float*)d_in[0];
  const float* w = (const float*)d_in[1];
  const float* b = (const float*)d_in[2];
  const int* neigh = (const int*)d_in[3];
  __hip_bfloat16* ws = (__hip_bfloat16*)d_ws;
  float* out = (float*)d_out;

  hipLaunchKernelGGL(prep_kernel, dim3(512), dim3(256), 0, stream, x, w, ws);
  hipLaunchKernelGGL(upconv_kernel, dim3(N_CHILD / BM), dim3(256), 0, stream,
                     neigh, ws, b, out);
}